// Round 2
// baseline (491.220 us; speedup 1.0000x reference)
//
#include <hip/hip_runtime.h>
#include <stdint.h>

static constexpr int HIN = 256, WIN = 256, HO = 254, WOUT = 254, NB = 8;
static constexpr int PLANE = HO * WOUT;       // 64516
static constexpr int PIX = NB * PLANE;        // 516128

typedef float f32x2 __attribute__((ext_vector_type(2)));

// Ring connectivity: prev atom j feeds next atoms (2j..2j+3) mod a_next.
// Morton-spread mask (j -> bit 2j), duplicate to (2j,2j+1), OR rotate-left-2.
__device__ __forceinline__ uint64_t spread_pairs(uint64_t mask, int a_next) {
  uint64_t s = mask;
  s = (s | (s << 16)) & 0x0000FFFF0000FFFFull;
  s = (s | (s << 8))  & 0x00FF00FF00FF00FFull;
  s = (s | (s << 4))  & 0x0F0F0F0F0F0F0F0Full;
  s = (s | (s << 2))  & 0x3333333333333333ull;
  s = (s | (s << 1))  & 0x5555555555555555ull;
  uint64_t pair = s | (s << 1);
  uint64_t lim = (a_next >= 64) ? ~0ull : ((1ull << a_next) - 1ull);
  uint64_t rot = ((pair << 2) | (pair >> (a_next - 2))) & lim;
  return (pair | rot) & lim;
}

// Bitonic sort (descending) of K uint32 in registers. K power of 2, fully
// unrolled => all indices static => stays in VGPRs. Pure v_min_u32/v_max_u32.
template<int K>
__device__ __forceinline__ void bsort_desc(uint32_t (&v)[K]) {
#pragma unroll
  for (int sz = 2; sz <= K; sz <<= 1) {
#pragma unroll
    for (int st = sz >> 1; st > 0; st >>= 1) {
#pragma unroll
      for (int i = 0; i < K; ++i) {
        int l = i ^ st;
        if (l > i) {
          uint32_t a = v[i], c = v[l];
          uint32_t mx = a > c ? a : c;
          uint32_t mn = a > c ? c : a;
          bool desc = ((i & sz) == 0);
          v[i] = desc ? mx : mn;
          v[l] = desc ? mn : mx;
        }
      }
    }
  }
}

// Bitonic cleanup merge (descending) of an already-bitonic K-sequence.
template<int K>
__device__ __forceinline__ void bmerge_desc(uint32_t (&v)[K]) {
#pragma unroll
  for (int st = K >> 1; st > 0; st >>= 1) {
#pragma unroll
    for (int i = 0; i < K; ++i) {
      int l = i ^ st;
      if (l > i) {
        uint32_t a = v[i], c = v[l];
        v[i] = a > c ? a : c;
        v[l] = a > c ? c : a;
      }
    }
  }
}

// One level. Conv numerics (validated round 7): single f32 accumulator from 0,
// sequential __fmaf_rn over the patch in (ky, kx, c) order — channels
// innermost — bias added last, separate add. The conv is packed TWO ATOMS per
// v_pk_fma_f32 chain: each half of the packed register is its own strictly
// sequential (ky,kx,c)-ordered FMA chain, so per-atom rounding is bit-identical
// to the scalar version (llvm.fma per lane == __fmaf_rn).
//
// Selection: jax top_k semantics — exactly K kept, ties at the boundary
// broken toward LOWEST channel index. Threshold m (K-th largest |act| WITH
// multiplicity) via grouped bitonic top-K on uint32 bit patterns of |act|.
// After the final merge, run[] holds exactly the top-K multiset (bitonic
// order), so quota = #{run[i] == m} — no N-wide base rescan needed.
template<int N, int K, bool GATE>
__device__ __forceinline__ uint64_t do_level(const float (&px)[27],
    const float* __restrict__ w, const float* __restrict__ b,
    int ch0, uint64_t allow, float* __restrict__ out, size_t out_base) {
  float act[N];
#pragma unroll
  for (int j = 0; j < N; j += 2) {
    const float* wp0 = w + (size_t)(ch0 + j) * 27;   // layout (c,ky,kx) per atom
    f32x2 acc; acc.x = 0.0f; acc.y = 0.0f;
#pragma unroll
    for (int ky = 0; ky < 3; ++ky)
#pragma unroll
      for (int kx = 0; kx < 3; ++kx)
#pragma unroll
        for (int c = 0; c < 3; ++c) {
          int t = c * 9 + ky * 3 + kx;              // source layout index
          f32x2 wv; wv.x = wp0[t]; wv.y = wp0[27 + t];
          f32x2 pv; pv.x = px[t]; pv.y = px[t];     // splat (op_sel-foldable)
          acc = __builtin_elementwise_fma(pv, wv, acc);  // (ky,kx,c) chain x2
        }
    float a0 = __fadd_rn(acc.x, b[ch0 + j]);        // bias after conv
    float a1 = __fadd_rn(acc.y, b[ch0 + j + 1]);
    if (GATE) {
      a0 = ((allow >> j) & 1ull) ? a0 : 0.0f;
      a1 = ((allow >> (j + 1)) & 1ull) ? a1 : 0.0f;
    }
    act[j] = a0;
    act[j + 1] = a1;
  }

  // ---- threshold via grouped bitonic top-K (G = N/K = 4 for all levels) ----
  constexpr int G = N / K;
  uint32_t run[K];
#pragma unroll
  for (int i = 0; i < K; ++i)
    run[i] = __float_as_uint(act[i]) & 0x7fffffffu;
  bsort_desc<K>(run);

#pragma unroll
  for (int g = 1; g < G; ++g) {
    uint32_t tmp[K];
#pragma unroll
    for (int i = 0; i < K; ++i)
      tmp[i] = __float_as_uint(act[g * K + i]) & 0x7fffffffu;
    bsort_desc<K>(tmp);
    // top-K of (run desc, tmp desc): elementwise max against reversed tmp.
    // After this, run[] holds the top-K multiset (bitonic sequence).
#pragma unroll
    for (int i = 0; i < K; ++i) {
      uint32_t c = tmp[K - 1 - i];
      run[i] = run[i] > c ? run[i] : c;
    }
    if (g < G - 1) bmerge_desc<K>(run);   // re-sort for the next merge
  }
  uint32_t mb = run[0];
#pragma unroll
  for (int i = 1; i < K; ++i) mb = mb < run[i] ? mb : run[i];
  float m = __uint_as_float(mb);    // K-th largest |act| with multiplicity

  // quota = #{top-K elements == m} = K - #{|a| > m}; identical to the old
  // base/quota computation but scans K elements instead of N.
  int quota = 0;
#pragma unroll
  for (int i = 0; i < K; ++i) quota += (run[i] == mb) ? 1 : 0;

  uint64_t msk = 0;
#pragma unroll
  for (int j = 0; j < N; ++j) {
    float aj = fabsf(act[j]);
    bool eq = (aj == m);
    bool keep = (aj > m) || (eq && quota > 0);
    quota -= eq ? 1 : 0;
    float v = keep ? act[j] : 0.0f;
    out[out_base + (size_t)(ch0 + j) * PLANE] = v;
    msk |= (v != 0.0f) ? (1ull << j) : 0ull;
  }
  return msk;
}

// __launch_bounds__(256, 4): 4 waves/SIMD => 128-VGPR cap. Peak live set
// ~act[64] + px splats + selection regs; marginal — watch VGPR/scratch.
__global__ __launch_bounds__(256, 4)
void hrtk_main(const float* __restrict__ x, const float* __restrict__ w,
               const float* __restrict__ b, float* __restrict__ out) {
  int p = blockIdx.x * blockDim.x + threadIdx.x;
  if (p >= PIX) return;
  int bi = p / PLANE;
  int r  = p % PLANE;
  int h  = r / WOUT;
  int wc = r % WOUT;

  float px[27];
  const float* xb = x + (size_t)bi * 3 * HIN * WIN;
#pragma unroll
  for (int c = 0; c < 3; ++c)
#pragma unroll
    for (int dy = 0; dy < 3; ++dy)
#pragma unroll
      for (int dx = 0; dx < 3; ++dx)
        px[c * 9 + dy * 3 + dx] =
            xb[c * HIN * WIN + (size_t)(h + dy) * WIN + (wc + dx)];

  size_t out_base = (size_t)bi * 120 * PLANE + (size_t)h * WOUT + wc;

  uint64_t m0 = do_level<8, 2, false>(px, w, b, 0, 0, out, out_base);
  uint64_t a1 = spread_pairs(m0, 16);
  uint64_t m1 = do_level<16, 4, true>(px, w, b, 8, a1, out, out_base);
  uint64_t a2 = spread_pairs(m1, 32);
  uint64_t m2 = do_level<32, 8, true>(px, w, b, 24, a2, out, out_base);
  uint64_t a3 = spread_pairs(m2, 64);
  (void)do_level<64, 16, true>(px, w, b, 56, a3, out, out_base);
}

extern "C" void kernel_launch(void* const* d_in, const int* in_sizes, int n_in,
                              void* d_out, int out_size, void* d_ws, size_t ws_size,
                              hipStream_t stream) {
  const float* x = (const float*)d_in[0];
  const float* w = (const float*)d_in[1];
  const float* b = (const float*)d_in[2];
  float* out = (float*)d_out;
  dim3 blk(256), grid((PIX + 255) / 256);
  hrtk_main<<<grid, blk, 0, stream>>>(x, w, b, out);
}

// Round 3
// 384.964 us; speedup vs baseline: 1.2760x; 1.2760x over previous
//
#include <hip/hip_runtime.h>
#include <stdint.h>

static constexpr int HIN = 256, WIN = 256, HO = 254, WOUT = 254, NB = 8;
static constexpr int PLANE = HO * WOUT;       // 64516
static constexpr int PIX = NB * PLANE;        // 516128

// Ring connectivity: prev atom j feeds next atoms (2j..2j+3) mod a_next.
// Morton-spread mask (j -> bit 2j), duplicate to (2j,2j+1), OR rotate-left-2.
__device__ __forceinline__ uint64_t spread_pairs(uint64_t mask, int a_next) {
  uint64_t s = mask;
  s = (s | (s << 16)) & 0x0000FFFF0000FFFFull;
  s = (s | (s << 8))  & 0x00FF00FF00FF00FFull;
  s = (s | (s << 4))  & 0x0F0F0F0F0F0F0F0Full;
  s = (s | (s << 2))  & 0x3333333333333333ull;
  s = (s | (s << 1))  & 0x5555555555555555ull;
  uint64_t pair = s | (s << 1);
  uint64_t lim = (a_next >= 64) ? ~0ull : ((1ull << a_next) - 1ull);
  uint64_t rot = ((pair << 2) | (pair >> (a_next - 2))) & lim;
  return (pair | rot) & lim;
}

// Bitonic sort (descending) of K uint32 in registers. K power of 2, fully
// unrolled => all indices static => stays in VGPRs. Pure v_min_u32/v_max_u32,
// no VCC/SALU chains, log^2-depth parallelism.
template<int K>
__device__ __forceinline__ void bsort_desc(uint32_t (&v)[K]) {
#pragma unroll
  for (int sz = 2; sz <= K; sz <<= 1) {
#pragma unroll
    for (int st = sz >> 1; st > 0; st >>= 1) {
#pragma unroll
      for (int i = 0; i < K; ++i) {
        int l = i ^ st;
        if (l > i) {
          uint32_t a = v[i], c = v[l];
          uint32_t mx = a > c ? a : c;
          uint32_t mn = a > c ? c : a;
          bool desc = ((i & sz) == 0);
          v[i] = desc ? mx : mn;
          v[l] = desc ? mn : mx;
        }
      }
    }
  }
}

// Bitonic cleanup merge (descending) of an already-bitonic K-sequence.
template<int K>
__device__ __forceinline__ void bmerge_desc(uint32_t (&v)[K]) {
#pragma unroll
  for (int st = K >> 1; st > 0; st >>= 1) {
#pragma unroll
    for (int i = 0; i < K; ++i) {
      int l = i ^ st;
      if (l > i) {
        uint32_t a = v[i], c = v[l];
        v[i] = a > c ? a : c;
        v[l] = a > c ? c : a;
      }
    }
  }
}

// One level. Conv numerics (validated round 7): single f32 accumulator from 0,
// sequential __fmaf_rn over the patch in (ky, kx, c) order — channels
// innermost (NHWC/HWIO im2col+sgemm mirror) — bias added last, separate add.
// SCALAR FMA only: the round-2 v_pk_fma_f32 experiment spilled act[] wholesale
// (VGPR 64, +200 MB scratch traffic) and regressed 173->288 us. Do not re-pack.
//
// Selection: jax top_k semantics — exactly K kept, ties at the boundary
// broken toward LOWEST channel index. Threshold m (K-th largest |act| WITH
// multiplicity) via grouped bitonic top-K on the uint32 bit patterns of |act|
// (bit order == value order for non-negative floats): sort N/K groups of K
// descending, merge pairwise keeping top-K. After the final merge run[] is
// exactly the top-K multiset, so quota = #{run[i]==mb} (K-scan, no N rescan).
template<int N, int K, bool GATE>
__device__ __forceinline__ uint64_t do_level(const float (&px)[27],
    const float* __restrict__ w, const float* __restrict__ b,
    int ch0, uint64_t allow, float* __restrict__ out, size_t out_base) {
  float act[N];
#pragma unroll
  for (int j = 0; j < N; ++j) {
    const float* wp = w + (size_t)(ch0 + j) * 27;   // layout (c,ky,kx) per atom
    float acc = 0.0f;
#pragma unroll
    for (int ky = 0; ky < 3; ++ky)
#pragma unroll
      for (int kx = 0; kx < 3; ++kx)
#pragma unroll
        for (int c = 0; c < 3; ++c) {
          int t = c * 9 + ky * 3 + kx;              // source layout index
          acc = __fmaf_rn(px[t], wp[t], acc);       // (ky,kx,c)-ordered FMA chain
        }
    acc = __fadd_rn(acc, b[ch0 + j]);               // bias after conv
    if (GATE) acc = ((allow >> j) & 1ull) ? acc : 0.0f;
    act[j] = acc;
  }

  // ---- threshold via grouped bitonic top-K (G = N/K = 4 for all levels) ----
  constexpr int G = N / K;
  uint32_t run[K];
#pragma unroll
  for (int i = 0; i < K; ++i)
    run[i] = __float_as_uint(act[i]) & 0x7fffffffu;
  bsort_desc<K>(run);

#pragma unroll
  for (int g = 1; g < G; ++g) {
    uint32_t tmp[K];
#pragma unroll
    for (int i = 0; i < K; ++i)
      tmp[i] = __float_as_uint(act[g * K + i]) & 0x7fffffffu;
    bsort_desc<K>(tmp);
    // top-K of (run desc, tmp desc): elementwise max against reversed tmp.
    // After this, run[] holds the top-K multiset (bitonic sequence).
#pragma unroll
    for (int i = 0; i < K; ++i) {
      uint32_t c = tmp[K - 1 - i];
      run[i] = run[i] > c ? run[i] : c;
    }
    if (g < G - 1) bmerge_desc<K>(run);   // re-sort for the next merge
  }
  uint32_t mb = run[0];
#pragma unroll
  for (int i = 1; i < K; ++i) mb = mb < run[i] ? mb : run[i];

  // quota = #{top-K elements == mb}; identical to K - #{|a| > m} but scans
  // only the K-element top multiset instead of all N activations.
  int quota = 0;
#pragma unroll
  for (int i = 0; i < K; ++i) quota += (run[i] == mb) ? 1 : 0;

  // Keep loop in the uint domain (same total order as float on |a| >= 0).
  uint64_t msk = 0;
#pragma unroll
  for (int j = 0; j < N; ++j) {
    uint32_t aj = __float_as_uint(act[j]) & 0x7fffffffu;
    bool eq = (aj == mb);
    bool keep = (aj > mb) || (eq && quota > 0);
    quota -= eq ? 1 : 0;
    float v = keep ? act[j] : 0.0f;
    out[out_base + (size_t)(ch0 + j) * PLANE] = v;
    msk |= (v != 0.0f) ? (1ull << j) : 0ull;
  }
  return msk;
}

// __launch_bounds__(256, 4): 4 waves/SIMD => 128-VGPR cap. Peak live set:
// level-3 conv px[27]+act[<=64] ~ 95; level-3 selection act[64]+run[16]+
// tmp[16] ~ 100 — fits 128 without scratch (round-1 build confirmed no-spill
// behavior at this structure; round-2 packing broke it).
__global__ __launch_bounds__(256, 4)
void hrtk_main(const float* __restrict__ x, const float* __restrict__ w,
               const float* __restrict__ b, float* __restrict__ out) {
  int p = blockIdx.x * blockDim.x + threadIdx.x;
  if (p >= PIX) return;
  int bi = p / PLANE;
  int r  = p % PLANE;
  int h  = r / WOUT;
  int wc = r % WOUT;

  float px[27];
  const float* xb = x + (size_t)bi * 3 * HIN * WIN;
#pragma unroll
  for (int c = 0; c < 3; ++c)
#pragma unroll
    for (int dy = 0; dy < 3; ++dy)
#pragma unroll
      for (int dx = 0; dx < 3; ++dx)
        px[c * 9 + dy * 3 + dx] =
            xb[c * HIN * WIN + (size_t)(h + dy) * WIN + (wc + dx)];

  size_t out_base = (size_t)bi * 120 * PLANE + (size_t)h * WOUT + wc;

  uint64_t m0 = do_level<8, 2, false>(px, w, b, 0, 0, out, out_base);
  uint64_t a1 = spread_pairs(m0, 16);
  uint64_t m1 = do_level<16, 4, true>(px, w, b, 8, a1, out, out_base);
  uint64_t a2 = spread_pairs(m1, 32);
  uint64_t m2 = do_level<32, 8, true>(px, w, b, 24, a2, out, out_base);
  uint64_t a3 = spread_pairs(m2, 64);
  (void)do_level<64, 16, true>(px, w, b, 56, a3, out, out_base);
}

extern "C" void kernel_launch(void* const* d_in, const int* in_sizes, int n_in,
                              void* d_out, int out_size, void* d_ws, size_t ws_size,
                              hipStream_t stream) {
  const float* x = (const float*)d_in[0];
  const float* w = (const float*)d_in[1];
  const float* b = (const float*)d_in[2];
  float* out = (float*)d_out;
  dim3 blk(256), grid((PIX + 255) / 256);
  hrtk_main<<<grid, blk, 0, stream>>>(x, w, b, out);
}

// Round 4
// 319.410 us; speedup vs baseline: 1.5379x; 1.2052x over previous
//
#include <hip/hip_runtime.h>
#include <stdint.h>

static constexpr int HIN = 256, WIN = 256, HO = 254, WOUT = 254, NB = 8;
static constexpr int PLANE = HO * WOUT;       // 64516
static constexpr int PIX = NB * PLANE;        // 516128
static constexpr int TOTAL_ATOMS = 120;

// Weights transposed to step-major order: g_wT[s*120 + atom] = w[atom*27 + t(s)]
// where step s = ky*9 + kx*3 + c enumerates the VALIDATED (ky,kx,c) FMA order
// and t(s) = c*9 + ky*3 + kx is the source (c,ky,kx) layout offset. This lets
// the conv loop run s = 0..26 ROLLED (small code) with per-s weight rows
// contiguous -> uniform scalar loads (SGPRs), while per-atom accumulation
// order stays bit-identical to the validated kernel.
__device__ float g_wT[27 * TOTAL_ATOMS];

__global__ void wprep(const float* __restrict__ w) {
  int i = blockIdx.x * blockDim.x + threadIdx.x;
  if (i >= 27 * TOTAL_ATOMS) return;
  int s = i / TOTAL_ATOMS, j = i % TOTAL_ATOMS;
  int ky = s / 9, kx = (s / 3) % 3, c = s % 3;
  g_wT[i] = w[j * 27 + c * 9 + ky * 3 + kx];
}

// Ring connectivity: prev atom j feeds next atoms (2j..2j+3) mod a_next.
__device__ __forceinline__ uint64_t spread_pairs(uint64_t mask, int a_next) {
  uint64_t s = mask;
  s = (s | (s << 16)) & 0x0000FFFF0000FFFFull;
  s = (s | (s << 8))  & 0x00FF00FF00FF00FFull;
  s = (s | (s << 4))  & 0x0F0F0F0F0F0F0F0Full;
  s = (s | (s << 2))  & 0x3333333333333333ull;
  s = (s | (s << 1))  & 0x5555555555555555ull;
  uint64_t pair = s | (s << 1);
  uint64_t lim = (a_next >= 64) ? ~0ull : ((1ull << a_next) - 1ull);
  uint64_t rot = ((pair << 2) | (pair >> (a_next - 2))) & lim;
  return (pair | rot) & lim;
}

// Bitonic sort (descending) of K uint32 in registers; fully unrolled, static
// indices, pure v_min_u32/v_max_u32.
template<int K>
__device__ __forceinline__ void bsort_desc(uint32_t (&v)[K]) {
#pragma unroll
  for (int sz = 2; sz <= K; sz <<= 1) {
#pragma unroll
    for (int st = sz >> 1; st > 0; st >>= 1) {
#pragma unroll
      for (int i = 0; i < K; ++i) {
        int l = i ^ st;
        if (l > i) {
          uint32_t a = v[i], c = v[l];
          uint32_t mx = a > c ? a : c;
          uint32_t mn = a > c ? c : a;
          bool desc = ((i & sz) == 0);
          v[i] = desc ? mx : mn;
          v[l] = desc ? mn : mx;
        }
      }
    }
  }
}

template<int K>
__device__ __forceinline__ void bmerge_desc(uint32_t (&v)[K]) {
#pragma unroll
  for (int st = K >> 1; st > 0; st >>= 1) {
#pragma unroll
    for (int i = 0; i < K; ++i) {
      int l = i ^ st;
      if (l > i) {
        uint32_t a = v[i], c = v[l];
        v[i] = a > c ? a : c;
        v[l] = a > c ? c : a;
      }
    }
  }
}

// One level. Conv numerics (validated): per atom, single f32 accumulator from
// 0, sequential __fmaf_rn in (ky,kx,c) step order (s ascending == identical
// chain), bias added last as separate __fadd_rn. Conv loop over s is ROLLED
// (I-cache footprint); inner j unrolled so act[] stays in VGPRs. px comes
// from LDS (per-thread row, stride 27 words -> 2 lanes/bank, conflict-free);
// weights from g_wT rows (uniform addresses -> scalar loads, SGPR operands).
//
// Selection: jax top_k semantics — exactly K kept, boundary ties broken
// toward LOWEST channel index. Threshold via grouped bitonic top-K on uint32
// bit patterns of |act|; after final merge run[] is the top-K multiset, so
// quota = #{run[i]==mb}. Keep loop in FLOAT domain (abs is a free input
// modifier on v_cmp; round-3's uint keep loop cost an extra v_and per atom).
template<int N, int K, bool GATE>
__device__ __forceinline__ uint64_t do_level(const float* __restrict__ pxl,
    const float* __restrict__ b, int ch0, uint64_t allow,
    float* __restrict__ out, size_t out_base) {
  float act[N];
#pragma unroll
  for (int j = 0; j < N; ++j) act[j] = 0.0f;

  float p = pxl[0];
#pragma unroll 1
  for (int s = 0; s < 27; ++s) {
    const float* wrow = g_wT + s * TOTAL_ATOMS + ch0;   // uniform -> s_load
    float pn = pxl[(s + 1 == 27) ? 0 : (s + 1)];        // prefetch next px
#pragma unroll
    for (int j = 0; j < N; ++j)
      act[j] = __fmaf_rn(p, wrow[j], act[j]);           // (ky,kx,c) chain
    p = pn;
  }
#pragma unroll
  for (int j = 0; j < N; ++j) {
    float a = __fadd_rn(act[j], b[ch0 + j]);            // bias after conv
    if (GATE) a = ((allow >> j) & 1ull) ? a : 0.0f;
    act[j] = a;
  }

  // ---- threshold via grouped bitonic top-K (G = N/K = 4 at all levels) ----
  constexpr int G = N / K;
  uint32_t run[K];
#pragma unroll
  for (int i = 0; i < K; ++i)
    run[i] = __float_as_uint(act[i]) & 0x7fffffffu;
  bsort_desc<K>(run);

#pragma unroll
  for (int g = 1; g < G; ++g) {
    uint32_t tmp[K];
#pragma unroll
    for (int i = 0; i < K; ++i)
      tmp[i] = __float_as_uint(act[g * K + i]) & 0x7fffffffu;
    bsort_desc<K>(tmp);
#pragma unroll
    for (int i = 0; i < K; ++i) {      // top-K of two desc runs
      uint32_t c = tmp[K - 1 - i];
      run[i] = run[i] > c ? run[i] : c;
    }
    if (g < G - 1) bmerge_desc<K>(run);
  }
  uint32_t mb = run[0];
#pragma unroll
  for (int i = 1; i < K; ++i) mb = mb < run[i] ? mb : run[i];
  float m = __uint_as_float(mb);       // K-th largest |act| with multiplicity

  int quota = 0;                       // #{top-K == m}: boundary-tie budget
#pragma unroll
  for (int i = 0; i < K; ++i) quota += (run[i] == mb) ? 1 : 0;

  uint64_t msk = 0;
#pragma unroll
  for (int j = 0; j < N; ++j) {
    float aj = fabsf(act[j]);
    bool eq = (aj == m);
    bool keep = (aj > m) || (eq && quota > 0);
    quota -= eq ? 1 : 0;
    float v = keep ? act[j] : 0.0f;
    out[out_base + (size_t)(ch0 + j) * PLANE] = v;
    msk |= (v != 0.0f) ? (1ull << j) : 0ull;
  }
  return msk;
}

// __launch_bounds__(256,4): 128-VGPR cap, 4 blocks/CU (LDS 27.6 KB/block ->
// 4 blocks fit 160 KB). No __syncthreads anywhere (LDS rows are per-thread
// private), so divergent early-return is safe.
__global__ __launch_bounds__(256, 4)
void hrtk_main(const float* __restrict__ x, const float* __restrict__ b,
               float* __restrict__ out) {
  __shared__ float smem[256 * 27];
  int p = blockIdx.x * blockDim.x + threadIdx.x;
  if (p >= PIX) return;
  int bi = p / PLANE;
  int r  = p % PLANE;
  int h  = r / WOUT;
  int wc = r % WOUT;

  // Stage the 3x3x3 patch into LDS in step order s = ky*9+kx*3+c, value from
  // source (c,ky,kx) — matches g_wT's step enumeration exactly.
  float* pxl = &smem[threadIdx.x * 27];
  const float* xb = x + (size_t)bi * 3 * HIN * WIN;
#pragma unroll
  for (int ky = 0; ky < 3; ++ky)
#pragma unroll
    for (int kx = 0; kx < 3; ++kx)
#pragma unroll
      for (int c = 0; c < 3; ++c)
        pxl[ky * 9 + kx * 3 + c] =
            xb[c * HIN * WIN + (size_t)(h + ky) * WIN + (wc + kx)];

  size_t out_base = (size_t)bi * 120 * PLANE + (size_t)h * WOUT + wc;

  uint64_t m0 = do_level<8, 2, false>(pxl, b, 0, 0, out, out_base);
  uint64_t a1 = spread_pairs(m0, 16);
  uint64_t m1 = do_level<16, 4, true>(pxl, b, 8, a1, out, out_base);
  uint64_t a2 = spread_pairs(m1, 32);
  uint64_t m2 = do_level<32, 8, true>(pxl, b, 24, a2, out, out_base);
  uint64_t a3 = spread_pairs(m2, 64);
  (void)do_level<64, 16, true>(pxl, b, 56, a3, out, out_base);
}

extern "C" void kernel_launch(void* const* d_in, const int* in_sizes, int n_in,
                              void* d_out, int out_size, void* d_ws, size_t ws_size,
                              hipStream_t stream) {
  const float* x = (const float*)d_in[0];
  const float* w = (const float*)d_in[1];
  const float* b = (const float*)d_in[2];
  float* out = (float*)d_out;

  // Stream-ordered: transpose weights into step-major layout, then main.
  wprep<<<dim3((27 * TOTAL_ATOMS + 255) / 256), dim3(256), 0, stream>>>(w);
  dim3 blk(256), grid((PIX + 255) / 256);
  hrtk_main<<<grid, blk, 0, stream>>>(x, b, out);
}